// Round 1
// baseline (147.841 us; speedup 1.0000x reference)
//
#include <hip/hip_runtime.h>

#define BATCH   131072
#define NS      300
#define H       100
#define NOSC    4
#define BLK     256

__global__ __launch_bounds__(BLK, 2) void lorentz_fused(
    const float* __restrict__ G,
    const float* __restrict__ W1,
    const float* __restrict__ b1,
    const float* __restrict__ W2,
    const float* __restrict__ b2,
    const float* __restrict__ Ww0,
    const float* __restrict__ Wwp,
    const float* __restrict__ Wg,
    float* __restrict__ out)
{
    // per-batch-element derived params: [tid][0..3]=w0^2, [4..7]=g^2, [8..11]=wp^2*g
    __shared__ float sP[BLK * 12];
    __shared__ float sW[NS];
    __shared__ float sWsq[NS];

    const int tid = threadIdx.x;
    const int b   = blockIdx.x * BLK + tid;

    // frequency table (fp32, matches jnp.arange(0.5, 5.0, 0.015))
    for (int k = tid; k < NS; k += BLK) {
        float w = 0.5f + (float)k * 0.015f;
        sW[k]   = w;
        sWsq[k] = w * w;
    }

    // ---- MLP trunk: one thread = one batch element ----
    float gin[8];
    {
        const float4* gp = (const float4*)(G + (size_t)b * 8);
        float4 a = gp[0], c = gp[1];
        gin[0] = a.x; gin[1] = a.y; gin[2] = a.z; gin[3] = a.w;
        gin[4] = c.x; gin[5] = c.y; gin[6] = c.z; gin[7] = c.w;
    }

    // layer 1: 8 -> 100, ReLU.  Fully unrolled -> h1 in registers (static idx).
    float h1[H];
#pragma unroll
    for (int j = 0; j < H; ++j) {
        float acc = b1[j];
#pragma unroll
        for (int k = 0; k < 8; ++k)
            acc = fmaf(gin[k], W1[j * 8 + k], acc);
        h1[j] = fmaxf(acc, 0.f);
    }

    // layer 2 (100 -> 100, ReLU) fused with the 3 bias-free heads:
    // h2[j] is consumed immediately, never stored.
    float aw0[NOSC] = {0.f, 0.f, 0.f, 0.f};
    float awp[NOSC] = {0.f, 0.f, 0.f, 0.f};
    float ag [NOSC] = {0.f, 0.f, 0.f, 0.f};

    for (int j = 0; j < H; ++j) {
        float acc = b2[j];
#pragma unroll
        for (int k = 0; k < H; ++k)
            acc = fmaf(h1[k], W2[j * H + k], acc);
        float h2 = fmaxf(acc, 0.f);
#pragma unroll
        for (int m = 0; m < NOSC; ++m) {
            aw0[m] = fmaf(h2, Ww0[m * H + j], aw0[m]);
            awp[m] = fmaf(h2, Wwp[m * H + j], awp[m]);
            ag [m] = fmaf(h2, Wg [m * H + j], ag [m]);
        }
    }

#pragma unroll
    for (int m = 0; m < NOSC; ++m) {
        float w0 = fmaxf(aw0[m], 0.f);
        float wp = fmaxf(awp[m], 0.f);
        float gg = fmaxf(ag [m], 0.f);
        sP[tid * 12 + m]     = w0 * w0;       // w0^2
        sP[tid * 12 + 4 + m] = gg * gg;       // g^2
        sP[tid * 12 + 8 + m] = wp * wp * gg;  // wp^2 * g  (numerator coeff; e2 = w * sum c/den)
    }
    __syncthreads();

    // ---- spectrum: block's output region [blockIdx*BLK*NS, ...) is contiguous.
    // thread t writes idx = it*BLK + t  -> fully coalesced stores.
    const size_t base = (size_t)blockIdx.x * (BLK * NS);
    for (int it = 0; it < NS; ++it) {
        int idx = it * BLK + tid;
        int bb  = idx / NS;            // const-divide -> magic mul
        int k   = idx - bb * NS;
        float w   = sW[k];
        float wsq = sWsq[k];
        float acc = 0.f;
#pragma unroll
        for (int m = 0; m < NOSC; ++m) {
            float w0sq = sP[bb * 12 + m];
            float gsq  = sP[bb * 12 + 4 + m];
            float c    = sP[bb * 12 + 8 + m];
            float t    = w0sq - wsq;
            float den  = fmaf(t, t, wsq * gsq);           // (w0^2-w^2)^2 + w^2 g^2
            acc        = fmaf(c, __builtin_amdgcn_rcpf(den), acc);
        }
        out[base + idx] = acc * w;
    }
}

extern "C" void kernel_launch(void* const* d_in, const int* in_sizes, int n_in,
                              void* d_out, int out_size, void* d_ws, size_t ws_size,
                              hipStream_t stream) {
    const float* G   = (const float*)d_in[0];
    const float* W1  = (const float*)d_in[1];
    const float* b1  = (const float*)d_in[2];
    const float* W2  = (const float*)d_in[3];
    const float* b2  = (const float*)d_in[4];
    const float* Ww0 = (const float*)d_in[5];
    const float* Wwp = (const float*)d_in[6];
    const float* Wg  = (const float*)d_in[7];
    float* out = (float*)d_out;

    dim3 grid(BATCH / BLK);   // 512 blocks, exact cover
    dim3 block(BLK);
    lorentz_fused<<<grid, block, 0, stream>>>(G, W1, b1, W2, b2, Ww0, Wwp, Wg, out);
}

// Round 2
// 117.353 us; speedup vs baseline: 1.2598x; 1.2598x over previous
//
#include <hip/hip_runtime.h>

#define BATCH 131072
#define NS    300
#define H     100
#define BLK   256
#define TILE4 (BLK * NS / 4)   /* 19200 float4 outputs per block */

/* macro repetition: M(a,b) for all (a,b) in 0..9 x 0..9 -> index a*10+b */
#define DIG(M,a) M(a,0) M(a,1) M(a,2) M(a,3) M(a,4) M(a,5) M(a,6) M(a,7) M(a,8) M(a,9)
#define DO100(M) DIG(M,0) DIG(M,1) DIG(M,2) DIG(M,3) DIG(M,4) DIG(M,5) DIG(M,6) DIG(M,7) DIG(M,8) DIG(M,9)

__global__ __launch_bounds__(BLK) __attribute__((amdgpu_waves_per_eu(2, 2)))
void lorentz_fused(const float* __restrict__ G,  const float* __restrict__ W1,
                   const float* __restrict__ b1, const float* __restrict__ W2,
                   const float* __restrict__ b2, const float* __restrict__ Ww0,
                   const float* __restrict__ Wwp, const float* __restrict__ Wg,
                   float* __restrict__ out)
{
    __shared__ float4 sP0[BLK];   /* w0^2  per osc (x,y,z,w = osc 0..3) */
    __shared__ float4 sP1[BLK];   /* g^2   per osc */
    __shared__ float4 sP2[BLK];   /* wp^2*g per osc */

    const int tid = threadIdx.x;
    const int b   = blockIdx.x * BLK + tid;

    /* ---- input: 8 features, two float4 loads ---- */
    const float4* gp = (const float4*)(G + (size_t)b * 8);
    const float4 gA = gp[0], gB = gp[1];
    const float g0 = gA.x, g1 = gA.y, g2 = gA.z, g3 = gA.w;
    const float g4 = gB.x, g5 = gB.y, g6 = gB.z, g7 = gB.w;

    /* ---- layer 1: 8 -> 100, ReLU.  h1 as 100 NAMED scalars (no alloca). ---- */
#define H1DECL(a,b) float h1_##a##b;
    DO100(H1DECL)
#undef H1DECL

#define L1(a,b) { const float* wr = W1 + ((a)*10+(b)) * 8;              \
        float s0 = fmaf(g0, wr[0], b1[(a)*10+(b)]);                     \
        float s1 = g1 * wr[1];                                          \
        s0 = fmaf(g2, wr[2], s0);  s1 = fmaf(g3, wr[3], s1);            \
        s0 = fmaf(g4, wr[4], s0);  s1 = fmaf(g5, wr[5], s1);            \
        s0 = fmaf(g6, wr[6], s0);  s1 = fmaf(g7, wr[7], s1);            \
        h1_##a##b = fmaxf(s0 + s1, 0.f); }
    DO100(L1)
#undef L1

    /* ---- layer 2 (100 -> 100, ReLU) fused with the 3 bias-free heads ---- */
    float4 aw0 = {0.f,0.f,0.f,0.f}, awp = {0.f,0.f,0.f,0.f}, agg = {0.f,0.f,0.f,0.f};

    for (int j = 0; j < H; ++j) {
        const float* wr = W2 + j * H;               /* uniform -> s_load */
        float acc[4] = { b2[j], 0.f, 0.f, 0.f };    /* 4 chains for ILP; const-indexed */
#define L2(a,b) acc[((a)*10+(b)) & 3] = fmaf(h1_##a##b, wr[(a)*10+(b)], acc[((a)*10+(b)) & 3]);
        DO100(L2)
#undef L2
        const float h2 = fmaxf((acc[0] + acc[1]) + (acc[2] + acc[3]), 0.f);

        aw0.x = fmaf(h2, Ww0[0*H + j], aw0.x);
        aw0.y = fmaf(h2, Ww0[1*H + j], aw0.y);
        aw0.z = fmaf(h2, Ww0[2*H + j], aw0.z);
        aw0.w = fmaf(h2, Ww0[3*H + j], aw0.w);
        awp.x = fmaf(h2, Wwp[0*H + j], awp.x);
        awp.y = fmaf(h2, Wwp[1*H + j], awp.y);
        awp.z = fmaf(h2, Wwp[2*H + j], awp.z);
        awp.w = fmaf(h2, Wwp[3*H + j], awp.w);
        agg.x = fmaf(h2, Wg [0*H + j], agg.x);
        agg.y = fmaf(h2, Wg [1*H + j], agg.y);
        agg.z = fmaf(h2, Wg [2*H + j], agg.z);
        agg.w = fmaf(h2, Wg [3*H + j], agg.w);
    }

    /* ---- derived oscillator params -> LDS ---- */
    {
        const float c0 = fmaxf(aw0.x, 0.f), c1 = fmaxf(aw0.y, 0.f),
                    c2 = fmaxf(aw0.z, 0.f), c3 = fmaxf(aw0.w, 0.f);
        const float q0 = fmaxf(agg.x, 0.f), q1 = fmaxf(agg.y, 0.f),
                    q2 = fmaxf(agg.z, 0.f), q3 = fmaxf(agg.w, 0.f);
        const float p0 = fmaxf(awp.x, 0.f), p1 = fmaxf(awp.y, 0.f),
                    p2 = fmaxf(awp.z, 0.f), p3 = fmaxf(awp.w, 0.f);
        sP0[tid] = make_float4(c0*c0, c1*c1, c2*c2, c3*c3);
        sP1[tid] = make_float4(q0*q0, q1*q1, q2*q2, q3*q3);
        sP2[tid] = make_float4(p0*p0*q0, p1*p1*q1, p2*p2*q2, p3*p3*q3);
    }
    __syncthreads();

    /* ---- spectrum: block writes its contiguous 256*300-float region.
       float4 per thread-iter; 4 | 300 so a quad never straddles an element.
       Single rcp via common denominator: all terms positive, no cancellation. */
    float4* out4 = (float4*)out;
    const int base4 = blockIdx.x * TILE4;

    for (int it = 0; it < TILE4 / BLK; ++it) {      /* 75 iterations */
        const int idx4 = it * BLK + tid;            /* [0, 19200) */
        const int e    = idx4 / 75;                 /* element in tile (0..255) */
        const int k4   = idx4 - e * 75;             /* quad within row (0..74) */

        const float4 P0 = sP0[e];                   /* <=2 distinct e per wave: broadcast */
        const float4 P1 = sP1[e];
        const float4 P2 = sP2[e];

        const float kb = (float)(k4 << 2);
        float4 r;
        float* rp = (float*)&r;
#pragma unroll
        for (int i = 0; i < 4; ++i) {
            const float w   = 0.5f + (kb + (float)i) * 0.015f;
            const float wsq = w * w;
            const float t0 = P0.x - wsq, t1 = P0.y - wsq,
                        t2 = P0.z - wsq, t3 = P0.w - wsq;
            const float d0 = fmaf(t0, t0, wsq * P1.x);
            const float d1 = fmaf(t1, t1, wsq * P1.y);
            const float d2 = fmaf(t2, t2, wsq * P1.z);
            const float d3 = fmaf(t3, t3, wsq * P1.w);
            const float d01 = d0 * d1, d23 = d2 * d3;
            const float D   = d01 * d23;
            const float n01 = fmaf(P2.y, d0, P2.x * d1);
            const float n23 = fmaf(P2.w, d2, P2.z * d3);
            const float N   = fmaf(n01, d23, n23 * d01);
            rp[i] = w * (N * __builtin_amdgcn_rcpf(D));
        }
        out4[base4 + idx4] = r;
    }
}

extern "C" void kernel_launch(void* const* d_in, const int* in_sizes, int n_in,
                              void* d_out, int out_size, void* d_ws, size_t ws_size,
                              hipStream_t stream) {
    const float* G   = (const float*)d_in[0];
    const float* W1  = (const float*)d_in[1];
    const float* b1  = (const float*)d_in[2];
    const float* W2  = (const float*)d_in[3];
    const float* b2  = (const float*)d_in[4];
    const float* Ww0 = (const float*)d_in[5];
    const float* Wwp = (const float*)d_in[6];
    const float* Wg  = (const float*)d_in[7];
    float* out = (float*)d_out;

    dim3 grid(BATCH / BLK);   /* 512 blocks */
    dim3 block(BLK);
    lorentz_fused<<<grid, block, 0, stream>>>(G, W1, b1, W2, b2, Ww0, Wwp, Wg, out);
}